// Round 15
// baseline (177.383 us; speedup 1.0000x reference)
//
#include <hip/hip_runtime.h>
#include <stdint.h>

// Problem: B=32, S=2048, E2=1024, D=512
//   c[b][d]    = b_att[d] + sum_k dec[b][k] * W_att[1024+k][d]
//   att[b][s]  = sum_d tanh( sum_e x[b][s][e]*W_att[e][d] + c[b][d] ) * v[d]
//   w          = softmax(att, axis=s)
//   out[b][e]  = sum_s w[b][s] * x[b][s][e]
//
// ws layout: [0,256K) attention f32[65536]; [256K,320K) cbias f32[16384];
//            [320K,320K+1MiB) W_enc bf16 "fragment image":
//   16B unit index  u = c*2048 + wn*256 + nf*64 + lane   (c=K-chunk of 32)
//   holds W_enc[c*32 + (lane>>4)*8 + j][wn*64 + nf*16 + (lane&15)], j=0..7
// => wave wn's B-fragment for (c,nf) is ONE coalesced 1KB global load,
//    exactly in MFMA B-operand layout.

typedef __attribute__((ext_vector_type(8))) __bf16 bf16x8;
typedef __attribute__((ext_vector_type(4))) float f32x4;
typedef __attribute__((ext_vector_type(4))) unsigned int u32x4;

__device__ __forceinline__ uint16_t f32_to_bf16_rne(float f) {
  union { float f; uint32_t u; } v; v.f = f;
  uint32_t u = v.u;
  return (uint16_t)((u + 0x7FFFu + ((u >> 16) & 1u)) >> 16);
}

__device__ __forceinline__ float tanh_fast(float x) {
  float e = __expf(2.0f * x);
  return 1.0f - 2.0f * __builtin_amdgcn_rcpf(e + 1.0f);
}

// ---------------- Kernel A: prep (unchanged) ----------------
__global__ __launch_bounds__(256) void prep_kernel(
    const float* __restrict__ dec,   // (32,512)
    const float* __restrict__ Watt,  // (1536,512)
    const float* __restrict__ batt,  // (512)
    float* __restrict__ cbias,       // ws (32*512)
    uint16_t* __restrict__ Wb,       // ws (1 MiB fragment image)
    float* __restrict__ out)         // d_out (32768) -> zero
{
  const int t = blockIdx.x * 256 + threadIdx.x;  // [0,16384)

  for (int i = t; i < 32768; i += 16384) out[i] = 0.0f;

  {
    const int b = t >> 9, d = t & 511;
    const float* wd = Watt + 1024 * 512 + d;
    const float* dv = dec + b * 512;
    float s0 = 0.f, s1 = 0.f, s2 = 0.f, s3 = 0.f;
    #pragma unroll 4
    for (int k = 0; k < 512; k += 4) {
      s0 += dv[k + 0] * wd[(k + 0) * 512];
      s1 += dv[k + 1] * wd[(k + 1) * 512];
      s2 += dv[k + 2] * wd[(k + 2) * 512];
      s3 += dv[k + 3] * wd[(k + 3) * 512];
    }
    cbias[t] = batt[d] + ((s0 + s1) + (s2 + s3));
  }

  // W fragment image: 65536 16-byte units, 4 per thread.
  uint4* WbV = (uint4*)Wb;
  #pragma unroll
  for (int i = 0; i < 4; ++i) {
    const int u   = t + 16384 * i;    // [0,65536)
    const int c   = u >> 11;          // K-chunk
    const int rem = u & 2047;
    const int wn  = rem >> 8;         // 0..7
    const int nf  = (rem >> 6) & 3;   // 0..3
    const int ln  = rem & 63;         // lane
    const int kb  = c * 32 + ((ln >> 4) << 3);
    const int d   = wn * 64 + nf * 16 + (ln & 15);
    uint32_t h[8];
    #pragma unroll
    for (int kk = 0; kk < 8; ++kk) {
      float f = Watt[(size_t)(kb + kk) * 512 + d];
      h[kk] = f32_to_bf16_rne(f);
    }
    uint4 val;
    val.x = h[0] | (h[1] << 16);
    val.y = h[2] | (h[3] << 16);
    val.z = h[4] | (h[5] << 16);
    val.w = h[6] | (h[7] << 16);
    WbV[u] = val;
  }
}

// ---------------- Kernel B: fused energy GEMM + tanh + dot(v), v9 ----------------
// v9 = v7 (best so far) + NT x-loads (keep W hot in L2) + 2-interval-deep
// A-prefetch (avA/avB rotation). B in regs, dbuf 1 interval ahead. LDS = A
// only (64x32 bf16 dbuf, 8 KB). 1024 blocks x 512 thr; 4 waves/SIMD.
__global__ __launch_bounds__(512, 4) void energy_kernel(
    const float* __restrict__ x,       // (65536,1024)
    const uint16_t* __restrict__ Wb,   // fragment image (1 MiB)
    const float* __restrict__ cbias,   // (32,512)
    const float* __restrict__ vvec,    // (512)
    float* __restrict__ att)           // (65536), fully overwritten
{
  __shared__ __align__(16) uint8_t AL[2][64 * 64];     // 2 x 4 KB : A 64r x 32k bf16

  const int tid  = threadIdx.x;
  const int lane = tid & 63;
  const int wave = tid >> 6;           // 0..7 = wn (64-col group)
  const int l15  = lane & 15;
  const int l4   = lane >> 4;
  const int brow0 = blockIdx.x * 64;
  const int b     = brow0 >> 11;

  // A staging: 1 float4/thread: r = tid>>3 in [0,64), q = tid&7
  const int r_st = tid >> 3, q_st = tid & 7;
  const int aoff = r_st * 64 + ((q_st * 8) ^ (((r_st >> 1) & 3) << 4));
  const float* asrc = x + (size_t)(brow0 + r_st) * 1024 + q_st * 4;
  // this wave's B slice: 4 frags x 1 KB per chunk, chunk stride 32 KB
  const uint8_t* wslice = (const uint8_t*)Wb + (size_t)wave * 4096 + (size_t)lane * 16;

  f32x4 acc[4][4];
  #pragma unroll
  for (int mf = 0; mf < 4; ++mf)
    #pragma unroll
    for (int nf = 0; nf < 4; ++nf)
      acc[mf][nf] = (f32x4){0.f, 0.f, 0.f, 0.f};

  // prologue: av 2-deep (chunks 0,1), B(0) fragments
  f32x4 avA = __builtin_nontemporal_load((const f32x4*)(asrc));
  f32x4 avB = __builtin_nontemporal_load((const f32x4*)(asrc + 32));
  bf16x8 bA[4], bB[4];
  {
    const bf16x8* bs = (const bf16x8*)(wslice);
    bA[0] = bs[0]; bA[1] = bs[64]; bA[2] = bs[128]; bA[3] = bs[192];
  }

// Per chunk c: ds_write A(c) from AV [counted vmcnt on AV, ~2 intervals old];
// reload AV with chunk c+2 (NT, stays in flight ~2 intervals);
// lgkmcnt(0); s_barrier [no vmcnt drain]; issue B(c+1) into BNXT;
// 4x { ds_read af; 4 MFMA with BCUR }.
// dbuf safety: wave writing A(c) has passed barrier(c-1) => all waves
// finished write A(c-1) => finished compute(c-2) which read AL[c&1].
#define CHUNK(C, BCUR, BNXT, AV)                                               \
  {                                                                            \
    const int c_ = (C);                                                        \
    uint8_t* Ab = AL[c_ & 1];                                                  \
    uint32_t lo_ = (uint32_t)f32_to_bf16_rne(AV.x) |                           \
                   ((uint32_t)f32_to_bf16_rne(AV.y) << 16);                    \
    uint32_t hi_ = (uint32_t)f32_to_bf16_rne(AV.z) |                           \
                   ((uint32_t)f32_to_bf16_rne(AV.w) << 16);                    \
    *(uint2*)(Ab + aoff) = make_uint2(lo_, hi_);                               \
    const int cp2_ = (c_ + 2 < 32) ? c_ + 2 : 31;                              \
    AV = __builtin_nontemporal_load((const f32x4*)(asrc + cp2_ * 32));         \
    const int cn_ = (c_ < 31) ? c_ + 1 : 31;                                   \
    asm volatile("s_waitcnt lgkmcnt(0)" ::: "memory");                         \
    __builtin_amdgcn_s_barrier();                                              \
    asm volatile("" ::: "memory");                                             \
    {                                                                          \
      const bf16x8* bs_ = (const bf16x8*)(wslice + (size_t)cn_ * 32768);       \
      BNXT[0] = bs_[0]; BNXT[1] = bs_[64];                                     \
      BNXT[2] = bs_[128]; BNXT[3] = bs_[192];                                  \
    }                                                                          \
    _Pragma("unroll")                                                          \
    for (int mf = 0; mf < 4; ++mf) {                                           \
      const int r_ = mf * 16 + l15;                                            \
      bf16x8 afm = *(const bf16x8*)(Ab + r_ * 64 +                             \
                                    ((l4 * 16) ^ (((r_ >> 1) & 3) << 4)));     \
      acc[mf][0] = __builtin_amdgcn_mfma_f32_16x16x32_bf16(afm, BCUR[0], acc[mf][0], 0, 0, 0); \
      acc[mf][1] = __builtin_amdgcn_mfma_f32_16x16x32_bf16(afm, BCUR[1], acc[mf][1], 0, 0, 0); \
      acc[mf][2] = __builtin_amdgcn_mfma_f32_16x16x32_bf16(afm, BCUR[2], acc[mf][2], 0, 0, 0); \
      acc[mf][3] = __builtin_amdgcn_mfma_f32_16x16x32_bf16(afm, BCUR[3], acc[mf][3], 0, 0, 0); \
    }                                                                          \
  }

  for (int c = 0; c < 32; c += 2) {
    CHUNK(c, bA, bB, avA);
    CHUNK(c + 1, bB, bA, avB);
  }
#undef CHUNK

  // ---- epilogue: tanh + dot(v); LDS-atomic reduce across the 8 waves ----
  float cb[4], vv[4];
  #pragma unroll
  for (int nf = 0; nf < 4; ++nf) {
    const int d = wave * 64 + nf * 16 + l15;
    cb[nf] = cbias[b * 512 + d];
    vv[nf] = vvec[d];
  }

  __syncthreads();                       // all waves done reading AL
  float* red = (float*)AL;               // reuse 256 B of A space
  if (tid < 64) red[tid] = 0.0f;
  __syncthreads();

  #pragma unroll
  for (int mf = 0; mf < 4; ++mf) {
    float s[4] = {0.f, 0.f, 0.f, 0.f};
    #pragma unroll
    for (int nf = 0; nf < 4; ++nf) {
      #pragma unroll
      for (int j = 0; j < 4; ++j) {
        const float e = acc[mf][nf][j] + cb[nf];
        s[j] += tanh_fast(e) * vv[nf];
      }
    }
    #pragma unroll
    for (int j = 0; j < 4; ++j) {
      float r = s[j];
      r += __shfl_xor(r, 1);
      r += __shfl_xor(r, 2);
      r += __shfl_xor(r, 4);
      r += __shfl_xor(r, 8);
      if (l15 == 0) atomicAdd(&red[mf * 16 + 4 * l4 + j], r);
    }
  }
  __syncthreads();
  if (tid < 64) att[brow0 + tid] = red[tid];
}

// ---------------- Probe: W-load + barrier skeleton ONLY (diagnostic) --------
// Read-only, writes nothing; replicates energy's B-fragment traffic and
// barrier cadence with no LDS/MFMA/x. Its dispatch dur isolates the W path:
// healthy pipeline => ~5-10 us; >=50 us => W path is the binder.
// Keepalive uses per-component "v" operands (32-bit each) -- the "v"
// constraint rejects 128-bit structs.
__global__ __launch_bounds__(512, 4) void probe_kernel(
    const unsigned int* __restrict__ Wb) {
  const int lane = threadIdx.x & 63;
  const int wave = threadIdx.x >> 6;
  const u32x4* wslice = (const u32x4*)((const uint8_t*)Wb + (size_t)wave * 4096 + (size_t)lane * 16);
  for (int c = 0; c < 32; ++c) {
    const u32x4* bs = wslice + (size_t)c * 2048;
    u32x4 b0 = bs[0], b1 = bs[64], b2 = bs[128], b3 = bs[192];
    asm volatile("" :: "v"(b0.x), "v"(b0.y), "v"(b0.z), "v"(b0.w),
                       "v"(b1.x), "v"(b1.y), "v"(b1.z), "v"(b1.w));
    asm volatile("" :: "v"(b2.x), "v"(b2.y), "v"(b2.z), "v"(b2.w),
                       "v"(b3.x), "v"(b3.y), "v"(b3.z), "v"(b3.w));
    __builtin_amdgcn_s_barrier();
  }
}

// ---------------- Kernel C: softmax over S (in place) ----------------
__global__ __launch_bounds__(256) void softmax_kernel(float* __restrict__ att) {
  const int b = blockIdx.x;
  float* row = att + b * 2048;
  const int tid = threadIdx.x;
  __shared__ float redm[4], reds[4];

  float vals[8];
  float m = -1e30f;
  #pragma unroll
  for (int i = 0; i < 8; ++i) { vals[i] = row[tid + 256 * i]; m = fmaxf(m, vals[i]); }
  #pragma unroll
  for (int msk = 1; msk < 64; msk <<= 1) m = fmaxf(m, __shfl_xor(m, msk));
  if ((tid & 63) == 0) redm[tid >> 6] = m;
  __syncthreads();
  m = fmaxf(fmaxf(redm[0], redm[1]), fmaxf(redm[2], redm[3]));

  float s = 0.f;
  #pragma unroll
  for (int i = 0; i < 8; ++i) { vals[i] = __expf(vals[i] - m); s += vals[i]; }
  #pragma unroll
  for (int msk = 1; msk < 64; msk <<= 1) s += __shfl_xor(s, msk);
  if ((tid & 63) == 0) reds[tid >> 6] = s;
  __syncthreads();
  const float inv = 1.0f / (((reds[0] + reds[1]) + (reds[2] + reds[3])));
  #pragma unroll
  for (int i = 0; i < 8; ++i) row[tid + 256 * i] = vals[i] * inv;
}

// ---------------- Kernel D: context = w @ x (round-7 config) ----------------
__global__ __launch_bounds__(256) void context_kernel(
    const float* __restrict__ x,   // (65536,1024)
    const float* __restrict__ w,   // (32,2048)
    float* __restrict__ out)       // (32,1024), pre-zeroed
{
  const int blk = blockIdx.x;
  const int b = blk >> 4, sc = blk & 15;
  const int tid = threadIdx.x;
  const float* xb = x + ((size_t)(b * 2048 + sc * 128)) * 1024 + tid * 4;
  const float* wb = w + b * 2048 + sc * 128;

  float4 acc = {0.f, 0.f, 0.f, 0.f};
  for (int si = 0; si < 128; ++si) {
    const float ww = wb[si];
    const float4 xv = *(const float4*)(xb + (size_t)si * 1024);
    acc.x += ww * xv.x;
    acc.y += ww * xv.y;
    acc.z += ww * xv.z;
    acc.w += ww * xv.w;
  }
  float* o = out + b * 1024 + tid * 4;
  atomicAdd(o + 0, acc.x);
  atomicAdd(o + 1, acc.y);
  atomicAdd(o + 2, acc.z);
  atomicAdd(o + 3, acc.w);
}

extern "C" void kernel_launch(void* const* d_in, const int* in_sizes, int n_in,
                              void* d_out, int out_size, void* d_ws, size_t ws_size,
                              hipStream_t stream) {
  const float* x    = (const float*)d_in[0];  // (32,2048,1024)
  const float* dec  = (const float*)d_in[1];  // (32,512)
  const float* Watt = (const float*)d_in[2];  // (1536,512)
  const float* batt = (const float*)d_in[3];  // (512)
  const float* v    = (const float*)d_in[4];  // (512)
  float* out = (float*)d_out;

  uint8_t* ws = (uint8_t*)d_ws;
  float*    att   = (float*)ws;                        // 256 KB
  float*    cbias = (float*)(ws + 256 * 1024);         // 64 KB
  uint16_t* Wb    = (uint16_t*)(ws + 320 * 1024);      // 1 MiB

  prep_kernel<<<64, 256, 0, stream>>>(dec, Watt, batt, cbias, Wb, out);
  energy_kernel<<<1024, 512, 0, stream>>>(x, Wb, cbias, v, att);
  probe_kernel<<<1024, 512, 0, stream>>>((const unsigned int*)Wb);
  softmax_kernel<<<32, 256, 0, stream>>>(att);
  context_kernel<<<512, 256, 0, stream>>>(x, att, out);
}